// Round 14
// baseline (432.468 us; speedup 1.0000x reference)
//
#include <hip/hip_runtime.h>

typedef unsigned short u16;
typedef __attribute__((ext_vector_type(8))) unsigned short u16x8;
typedef __attribute__((ext_vector_type(4))) unsigned short u16x4;
typedef __attribute__((ext_vector_type(4))) float f32x4;

#define DEVI __device__ __forceinline__

// ---------------- helpers ----------------
DEVI u16 f2bf(float f){
  unsigned u = __float_as_uint(f);
  u += 0x7FFFu + ((u >> 16) & 1u);      // round-to-nearest-even
  return (u16)(u >> 16);
}

DEVI float bf2f(u16 b){
  return __uint_as_float((unsigned)b << 16);
}

DEVI void gload16(const void* g, void* l){
  __builtin_amdgcn_global_load_lds((const __attribute__((address_space(1))) void*)g,
                                   (__attribute__((address_space(3))) void*)l, 16, 0, 0);
}

DEVI float wave_sum(float v){
#pragma unroll
  for (int o = 32; o; o >>= 1) v += __shfl_xor(v, o, 64);
  return v;
}

#define MFMA16(a,b,c) __builtin_amdgcn_mfma_f32_16x16x32_bf16((a),(b),(c),0,0,0)

// ---------------- 4-tile pipelined 64x64 transpose group (256x64 region) ----
// tb points to float[2][64][65] in LDS.
DEVI void trans4(const float* __restrict__ in, u16* __restrict__ out,
                 int R, int C, int r0b, int c0, float* tb){
  const int rr0 = threadIdx.x >> 4, cc = (threadIdx.x & 15) * 4;
  float4 rv[4];
#define TLOAD(tt)                                                             \
  { _Pragma("unroll")                                                         \
    for (int it = 0; it < 4; it++)                                            \
      rv[it] = *(const float4*)(in + (size_t)(r0b + (tt)*64 + rr0 + it*16) * C + c0 + cc); }
#define TDSW(buf)                                                             \
  { _Pragma("unroll")                                                         \
    for (int it = 0; it < 4; it++){                                           \
      const int rr = rr0 + it*16;                                             \
      float* tr = tb + ((buf)*64 + rr) * 65 + cc;                             \
      tr[0] = rv[it].x; tr[1] = rv[it].y; tr[2] = rv[it].z; tr[3] = rv[it].w; } }
#define TWOUT(buf, tt)                                                        \
  { _Pragma("unroll")                                                         \
    for (int it2 = 0; it2 < 2; it2++){                                        \
      const int chunk = threadIdx.x + it2 * 256;                              \
      const int c = chunk >> 3, q = (chunk & 7) * 8;                          \
      union { u16x8 v8; u16 e[8]; } ob;                                       \
      _Pragma("unroll")                                                       \
      for (int i = 0; i < 8; i++) ob.e[i] = f2bf(tb[((buf)*64 + q + i) * 65 + c]); \
      *(u16x8*)(out + (size_t)(c0 + c) * R + r0b + (tt)*64 + q) = ob.v8; } }

  TLOAD(0); TDSW(0);
  __syncthreads();
#pragma unroll
  for (int tt = 0; tt < 4; tt++){
    const int buf = tt & 1;
    if (tt < 3) TLOAD(tt + 1);           // loads in flight over write-out
    TWOUT(buf, tt);
    if (tt < 3) TDSW(buf ^ 1);
    __syncthreads();
  }
#undef TLOAD
#undef TDSW
#undef TWOUT
}

// ---------------- prep_A: Wk/Wv transposes + enc convert + LN(dec_in) -------
// flat: [0,512) Wk/Wv  [512,1536) enc  [1536,2560) LN+copy
__global__ __launch_bounds__(256) void prepA_k(
    const float* __restrict__ Wk, const float* __restrict__ Wv,
    const float* __restrict__ enc, const float* __restrict__ dec_in,
    float* __restrict__ x, u16* __restrict__ xn,
    u16* __restrict__ Wkt, u16* __restrict__ Wvt, u16* __restrict__ encb){
  __shared__ __align__(16) float tb[2 * 64 * 65];
  const int t = blockIdx.x;
  if (t < 512){
    const int sel = t >> 8, t2 = t & 255, mat = t2 >> 6, gi = t2 & 63;
    const float* in = (sel ? Wv : Wk) + (size_t)mat * 1048576;
    u16* out = (sel ? Wvt : Wkt) + (size_t)mat * 1048576;
    trans4(in, out, 1024, 1024, (gi & 3) << 8, (gi >> 2) << 6, tb);
  } else if (t < 1536){                   // enc f32 -> bf16
    const int i = (t - 512) * 256 + threadIdx.x;
    float4 v = ((const float4*)enc)[i];
    u16x4 o = { f2bf(v.x), f2bf(v.y), f2bf(v.z), f2bf(v.w) };
    ((u16x4*)encb)[i] = o;
  } else {                                // LN + residual copy
    const int row = t - 1536, tid = threadIdx.x;
    const float4 v = ((const float4*)(dec_in + (size_t)row * 1024))[tid];
    ((float4*)x)[(size_t)row * 256 + tid] = v;
    __shared__ float sb[8];
    const int wid = tid >> 6, lane = tid & 63;
    float s = wave_sum(v.x + v.y + v.z + v.w);
    if (lane == 0) sb[wid] = s;
    __syncthreads();
    const float mean = (sb[0] + sb[1] + sb[2] + sb[3]) * (1.0f / 1024.0f);
    const float dx = v.x - mean, dy = v.y - mean, dz = v.z - mean, dw = v.w - mean;
    float q = wave_sum(dx*dx + dy*dy + dz*dz + dw*dw);
    if (lane == 0) sb[4 + wid] = q;
    __syncthreads();
    const float sd = sqrtf((sb[4] + sb[5] + sb[6] + sb[7]) * (1.0f / 1024.0f));
    const float inv = 1.0f / (sd + 1e-6f);
    u16x4 o = { f2bf(dx*inv), f2bf(dy*inv), f2bf(dz*inv), f2bf(dw*inv) };
    ((u16x4*)xn)[(size_t)row * 256 + tid] = o;
  }
}

// ---------------- 128xBN GEMM core (unchanged, proven) -----------------------
// MODE 0: bf16  3: bf16 relu(+bias)  5: f32 partial  6: V^T scatter
template<int MODE, int BN>
DEVI void gemm128_core(const u16* A, int lda, const u16* Bt, int ldb,
                       int Klen, int Nd, void* Cout,
                       const float* bias, u16* Als, u16* Bls, int row0, int col0){
  constexpr int WN = BN / 2, FN = BN / 32;
  constexpr int BSZ = BN * 64;
  const int tid = threadIdx.x;
  const int wid = tid >> 6, lane = tid & 63;
  const int wm = wid >> 1, wn = wid & 1;
  const int lrow = lane & 15, g = lane >> 4, e7 = lane & 7;
  f32x4 acc[4][FN] = {};

  const int scol = ((lane & 7) ^ ((lane >> 3) & 7)) * 8;
  const u16* Ag = A + (size_t)(row0 + wid*8 + (lane >> 3)) * lda + scol;
  const u16* Bg = Bt + (size_t)(col0 + wid*8 + (lane >> 3)) * ldb + scol;
  const int dst0 = wid * 512;
  const int nt = Klen >> 6;

#define STAGE128(buf, k0)                                                     \
  {                                                                           \
    _Pragma("unroll")                                                         \
    for (int q = 0; q < 4; q++)                                               \
      gload16(Ag + (size_t)q*32*lda + (k0), Als + (buf)*8192 + dst0 + q*2048);\
    _Pragma("unroll")                                                         \
    for (int q = 0; q < BN/32; q++)                                           \
      gload16(Bg + (size_t)q*32*ldb + (k0), Bls + (buf)*BSZ + dst0 + q*2048); \
  }

  STAGE128(0, 0);
  __syncthreads();

  for (int t = 0; t < nt; t++){
    const int cur = t & 1;
    if (t + 1 < nt) STAGE128(cur ^ 1, (t + 1) << 6);
    const u16* Ab = Als + cur * 8192;
    const u16* Bb = Bls + cur * BSZ;
#pragma unroll
    for (int ks = 0; ks < 2; ks++){
      const int sl = (((ks << 2) + g) ^ e7) << 3;
      u16x8 av[4], bv[FN];
#pragma unroll
      for (int mi = 0; mi < 4; mi++)
        av[mi] = *(const u16x8*)(Ab + (wm*64 + mi*16 + lrow) * 64 + sl);
#pragma unroll
      for (int ni = 0; ni < FN; ni++)
        bv[ni] = *(const u16x8*)(Bb + (wn*WN + ni*16 + lrow) * 64 + sl);
#pragma unroll
      for (int mi = 0; mi < 4; mi++)
#pragma unroll
        for (int ni = 0; ni < FN; ni++)
          acc[mi][ni] = MFMA16(av[mi], bv[ni], acc[mi][ni]);
    }
    __syncthreads();
  }
#undef STAGE128

#pragma unroll
  for (int mi = 0; mi < 4; mi++){
#pragma unroll
    for (int ni = 0; ni < FN; ni++){
      const int col = col0 + wn*WN + ni*16 + lrow;
#pragma unroll
      for (int j = 0; j < 4; j++){
        const int row = row0 + wm*64 + mi*16 + g*4 + j;
        float v = acc[mi][ni][j];
        if (MODE == 3) v = fmaxf(v + bias[col], 0.0f);
        if (MODE == 0 || MODE == 3)
          ((u16*)Cout)[(size_t)row * Nd + col] = f2bf(v);
        else if (MODE == 6)
          ((u16*)Cout)[(size_t)((col >> 9)*16 + (row >> 6)) * 32768
                       + (row & 63) * 512 + (col & 511)] = f2bf(v);
        else
          ((float*)Cout)[(size_t)row * Nd + col] = v;
      }
    }
  }
}

// ---------------- prep_B + gemmKV merged, INTERLEAVED dispatch ---------------
// Groups of 11 blocks = {2 gemmKV + 9 prep}: GEMM blocks (MFMA-heavy) are
// uniformly spread through dispatch order so every co-resident cohort mixes
// MFMA-heavy and HBM-heavy work. 512 groups x 11 = 5632 blocks.
// prep idx regions: [0,256) Wq  [256,512) Wo  [512,1536) Wf1
//                   [1536,2560) Wf2  [2560,4608) qsbias
// gemm idx [0,1024): z = idx>>7 (layer*2+kv), y = (idx>>4)&7, x = idx&15
__global__ __launch_bounds__(256) void prepB_gemmKV_k(
    const float* __restrict__ Wq, const float* __restrict__ Wo,
    const float* __restrict__ Wf1, const float* __restrict__ Wf2,
    const float* __restrict__ dist,
    const float* __restrict__ Wth0, const float* __restrict__ bth0,
    const float* __restrict__ Wto0, const float* __restrict__ bto0,
    const u16* __restrict__ encb, const u16* __restrict__ Wkt,
    const u16* __restrict__ Wvt,
    u16* __restrict__ Wqt, u16* __restrict__ Wot,
    u16* __restrict__ Wf1t, u16* __restrict__ Wf2t,
    u16* __restrict__ qs0, u16* __restrict__ Kb, u16* __restrict__ Vt){
  __shared__ __align__(16) char smem[49152];
  const int bid = blockIdx.x;
  const int grp = bid / 11, slot = bid % 11;
  if (slot < 2){                          // gemmKV block
    u16* Als = (u16*)smem;                // 2*8192 elems = 32 KB
    u16* Bls = (u16*)(smem + 32768);      // 2*4096 elems = 16 KB
    const int t2 = grp * 2 + slot;        // [0,1024)
    const int z = t2 >> 7, rem = t2 & 127;
    const int y = rem >> 4, xb = rem & 15;
    const int l = z >> 1;
    if ((z & 1) == 0)
      gemm128_core<0, 64>(encb, 1024, Wkt + (size_t)l*1048576, 1024, 1024, 1024,
                          Kb + (size_t)l*1048576, nullptr,
                          Als, Bls, y * 128, xb * 64);
    else   // C[h'][b*512+t] = Wvt @ encb^T, scattered into Vt[(b,n,h),t]
      gemm128_core<6, 64>(Wvt + (size_t)l*1048576, 1024, encb, 1024, 1024, 1024,
                          Vt + (size_t)l*1048576, nullptr,
                          Als, Bls, y * 128, xb * 64);
    return;
  }
  const int idx = grp * 9 + (slot - 2);   // [0,4608)
  if (idx < 2560){
    float* tb = (float*)smem;
    if (idx < 512){                       // Wq / Wo
      const int sel = idx >> 8, t2 = idx & 255, mat = t2 >> 6, gi = t2 & 63;
      trans4((sel ? Wo : Wq) + (size_t)mat * 1048576,
             (sel ? Wot : Wqt) + (size_t)mat * 1048576,
             1024, 1024, (gi & 3) << 8, (gi >> 2) << 6, tb);
    } else if (idx < 1536){
      const int t2 = idx - 512, mat = t2 >> 8, gi = t2 & 255;
      trans4(Wf1 + (size_t)mat * 4194304, Wf1t + (size_t)mat * 4194304,
             1024, 4096, (gi & 3) << 8, (gi >> 2) << 6, tb);
    } else {
      const int t2 = idx - 1536, mat = t2 >> 8, gi = t2 & 255;
      trans4(Wf2 + (size_t)mat * 4194304, Wf2t + (size_t)mat * 4194304,
             4096, 1024, (gi >> 4) << 8, (gi & 15) << 6, tb);
    }
  } else {                                // qsbias -> bf16
    const int bi = idx - 2560, ly = bi >> 9, xi = bi & 511;
    const float* Wth = Wth0 + ly*32;
    const float* bth = bth0 + ly*32;
    const float* Wto = Wto0 + ly*32;
    u16* qs = qs0 + (size_t)ly * 524288;
    const int i2 = xi * 256 + threadIdx.x;
    float4 s4 = ((const float4*)dist)[i2];
    float sv[4] = { s4.x, s4.y, s4.z, s4.w };
    float r[4];
    const float b0 = bto0[ly];
#pragma unroll
    for (int c = 0; c < 4; c++) r[c] = b0;
#pragma unroll
    for (int k = 0; k < 32; k++){
      const float wk = Wth[k], bk = bth[k], ok = Wto[k];
#pragma unroll
      for (int c = 0; c < 4; c++){
        float h = fmaxf(sv[c] * wk + bk, 0.0f);
        r[c] += h * ok;
      }
    }
    u16x4 o = { f2bf(r[0]), f2bf(r[1]), f2bf(r[2]), f2bf(r[3]) };
    ((u16x4*)qs)[i2] = o;
  }
}

template<int MODE>
__global__ __launch_bounds__(256) void gemm128_k(const u16* __restrict__ A, int lda,
    const u16* __restrict__ Bt, int ldb, int Klen, int Nd, void* __restrict__ Cout,
    const float* __restrict__ bias){
  __shared__ __align__(16) u16 Als[2 * 8192];
  __shared__ __align__(16) u16 Bls[2 * 4096];
  gemm128_core<MODE, 64>(A, lda, Bt, ldb, Klen, Nd, Cout, bias,
                         Als, Bls, blockIdx.y * 128, blockIdx.x * 64);
}

// split-K=4 GEMM into f32 partials (Nd=1024 always)
__global__ __launch_bounds__(256) void gemm_splitk_k(const u16* __restrict__ A, int lda,
    const u16* __restrict__ Bt, int ldb, int Klen, float* __restrict__ part){
  __shared__ __align__(16) u16 Als[2 * 8192];
  __shared__ __align__(16) u16 Bls[2 * 4096];
  const int z = blockIdx.z;
  gemm128_core<5, 64>(A + (size_t)z * Klen, lda, Bt + (size_t)z * Klen, ldb, Klen, 1024,
                      part + (size_t)z * 1048576, nullptr,
                      Als, Bls, blockIdx.y * 128, blockIdx.x * 64);
}

// ---------------- reduce + layernorm ----------------
template<int BIAS, int LAST>
__global__ __launch_bounds__(256) void reduce_ln_k(const float* __restrict__ part,
    const float* __restrict__ bias, float* __restrict__ x, u16* __restrict__ xn,
    float* __restrict__ dout){
  const int row = blockIdx.x, tid = threadIdx.x;
  const size_t idx = (size_t)row * 256 + tid;
  float4 v = ((const float4*)x)[idx];
  float4 p0 = ((const float4*)part)[idx];
  float4 p1 = ((const float4*)(part + 1048576))[idx];
  float4 p2 = ((const float4*)(part + 2097152))[idx];
  float4 p3 = ((const float4*)(part + 3145728))[idx];
  v.x += p0.x + p1.x + p2.x + p3.x;
  v.y += p0.y + p1.y + p2.y + p3.y;
  v.z += p0.z + p1.z + p2.z + p3.z;
  v.w += p0.w + p1.w + p2.w + p3.w;
  if (BIAS){
    const float4 b = *(const float4*)(bias + tid * 4);
    v.x += b.x; v.y += b.y; v.z += b.z; v.w += b.w;
  }
  if (!LAST) ((float4*)x)[idx] = v;

  __shared__ float sb[8];
  const int wid = tid >> 6, lane = tid & 63;
  float s = wave_sum(v.x + v.y + v.z + v.w);
  if (lane == 0) sb[wid] = s;
  __syncthreads();
  const float mean = (sb[0] + sb[1] + sb[2] + sb[3]) * (1.0f / 1024.0f);
  const float dx = v.x - mean, dy = v.y - mean, dz = v.z - mean, dw = v.w - mean;
  float q = wave_sum(dx*dx + dy*dy + dz*dz + dw*dw);
  if (lane == 0) sb[4 + wid] = q;
  __syncthreads();
  const float sd = sqrtf((sb[4] + sb[5] + sb[6] + sb[7]) * (1.0f / 1024.0f));
  const float inv = 1.0f / (sd + 1e-6f);
  if (LAST){
    ((float4*)dout)[idx] = make_float4(dx*inv, dy*inv, dz*inv, dw*inv);
  } else {
    u16x4 o = { f2bf(dx*inv), f2bf(dy*inv), f2bf(dz*inv), f2bf(dw*inv) };
    ((u16x4*)xn)[idx] = o;
  }
}

// ---------------- fused flash attention (Q-projection fused in) -------------
// grid (n=16, ftile=8, b=2); 4 waves, wave w owns 16 q-rows. 2 blocks/CU.
__global__ __launch_bounds__(256, 2) void attn_k(const u16* __restrict__ xn,
    const u16* __restrict__ Wqt,
    const u16* __restrict__ Kb, const u16* __restrict__ Vt,
    const u16* __restrict__ qs, const float* __restrict__ abias,
    u16* __restrict__ aout){
  const int n = blockIdx.x, f0 = blockIdx.y * 64, b = blockIdx.z;
  const int w = threadIdx.x >> 6, lane = threadIdx.x & 63;
  const int l15 = lane & 15, g = lane >> 4, e7 = lane & 7;
  const int fw = f0 + w * 16;
  __shared__ __align__(16) u16 Pl[4][16 * 512];   // 64 KB
  u16* pw = &Pl[w][0];

  u16x8 qf0, qf1;
  {
    u16* Als = &Pl[0][0];
    u16* Bls = &Pl[1][0];
    const int wm = w >> 1, wn = w & 1;
    f32x4 qac[2][2] = {};
    const int scol = ((lane & 7) ^ ((lane >> 3) & 7)) * 8;
    const u16* Ag = xn + (size_t)(b*512 + f0 + w*8 + (lane >> 3)) * 1024 + scol;
    const u16* Bg = Wqt + (size_t)(n*64 + w*8 + (lane >> 3)) * 1024 + scol;
    const int dq = w * 512;

#define STAGEQ(buf, k0)                                         \
    gload16(Ag + (k0),            Als + (buf)*4096 + dq);       \
    gload16(Ag + 32*1024 + (k0),  Als + (buf)*4096 + dq + 2048);\
    gload16(Bg + (k0),            Bls + (buf)*4096 + dq);       \
    gload16(Bg + 32*1024 + (k0),  Bls + (buf)*4096 + dq + 2048);

    STAGEQ(0, 0);
    __syncthreads();
    for (int t = 0; t < 16; t++){
      const int cur = t & 1;
      if (t < 15){ STAGEQ(cur ^ 1, (t + 1) << 6); }
      const u16* Ab = Als + cur * 4096;
      const u16* Bb = Bls + cur * 4096;
#pragma unroll
      for (int ks = 0; ks < 2; ks++){
        const int sl = (((ks << 2) + g) ^ e7) << 3;
        u16x8 av[2], bv[2];
#pragma unroll
        for (int mi = 0; mi < 2; mi++)
          av[mi] = *(const u16x8*)(Ab + (wm*32 + mi*16 + l15) * 64 + sl);
#pragma unroll
        for (int ni = 0; ni < 2; ni++)
          bv[ni] = *(const u16x8*)(Bb + (wn*32 + ni*16 + l15) * 64 + sl);
#pragma unroll
        for (int mi = 0; mi < 2; mi++)
#pragma unroll
          for (int ni = 0; ni < 2; ni++)
            qac[mi][ni] = MFMA16(av[mi], bv[ni], qac[mi][ni]);
      }
      __syncthreads();
    }
#undef STAGEQ

    u16* Qt = &Pl[2][0];
#pragma unroll
    for (int mi = 0; mi < 2; mi++)
#pragma unroll
      for (int ni = 0; ni < 2; ni++)
#pragma unroll
        for (int j = 0; j < 4; j++){
          const int r = wm*32 + mi*16 + g*4 + j;
          const int c = wn*32 + ni*16 + l15;
          const int byte = r*128 + (((c >> 3) ^ (r & 7)) << 4) + (c & 7)*2;
          *(u16*)((char*)Qt + byte) = f2bf(qac[mi][ni][j] * 0.125f);
        }
    __syncthreads();
    const int r = w*16 + l15;
    const char* qrow = (char*)Qt + r*128;
    qf0 = *(const u16x8*)(qrow + ((g ^ (r & 7)) << 4));
    qf1 = *(const u16x8*)(qrow + (((4 + g) ^ (r & 7)) << 4));
    __syncthreads();
  }

  // QK^T: acc[tf] holds S[fw+l15][tf*16 + g*4 + j]
  f32x4 acc[32];
  const u16* kp = Kb + ((size_t)b*512 + l15) * 1024 + n*64 + g*8;
#pragma unroll
  for (int tf = 0; tf < 32; tf++){
    u16x8 k0 = *(const u16x8*)(kp + (size_t)tf*16*1024);
    u16x8 k1 = *(const u16x8*)(kp + (size_t)tf*16*1024 + 32);
    f32x4 z = {0.f, 0.f, 0.f, 0.f};
    z = MFMA16(k0, qf0, z);
    acc[tf] = MFMA16(k1, qf1, z);
  }

  // + qs bias (bf16) + attn bias, row max
  const u16* qsp = qs + ((size_t)b*512 + fw + l15) * 512 + g*4;
  const float* abp = abias + (size_t)b*512 + g*4;
  float m = -3.0e38f;
#pragma unroll
  for (int tf = 0; tf < 32; tf++){
    u16x4 qv = *(const u16x4*)(qsp + tf*16);
    float4 av = *(const float4*)(abp + tf*16);
    acc[tf][0] += bf2f(qv[0]) + av.x;
    acc[tf][1] += bf2f(qv[1]) + av.y;
    acc[tf][2] += bf2f(qv[2]) + av.z;
    acc[tf][3] += bf2f(qv[3]) + av.w;
    m = fmaxf(m, fmaxf(fmaxf(acc[tf][0], acc[tf][1]), fmaxf(acc[tf][2], acc[tf][3])));
  }
  m = fmaxf(m, __shfl_xor(m, 16, 64));
  m = fmaxf(m, __shfl_xor(m, 32, 64));

  float s = 0.f;
#pragma unroll
  for (int tf = 0; tf < 32; tf++){
#pragma unroll
    for (int j = 0; j < 4; j++){
      float e = __expf(acc[tf][j] - m);
      acc[tf][j] = e; s += e;
    }
  }
  s += __shfl_xor(s, 16, 64);
  s += __shfl_xor(s, 32, 64);
  const float inv = 1.0f / s;
  float invj[4];
#pragma unroll
  for (int j = 0; j < 4; j++) invj[j] = __shfl(inv, g*4 + j, 64);

  // store unnormalized P (<=1) row-major [16][512] bf16, chunk-swizzled
#pragma unroll
  for (int tf = 0; tf < 32; tf++){
    const int chunk = tf*2 + (g >> 1);
    const int boff = (l15 << 10) + ((chunk ^ e7) << 4) + ((g & 1) << 3);
    u16x4 pk = { f2bf(acc[tf][0]), f2bf(acc[tf][1]), f2bf(acc[tf][2]), f2bf(acc[tf][3]) };
    *(u16x4*)((char*)pw + boff) = pk;
  }

  // PV: O[f][h] = P[f][:] @ V[:][h];  V^T frags direct from global (L2-resident)
  f32x4 oacc[4] = {};
  const u16* vp = Vt + ((size_t)(b*16 + n)*64 + l15) * 512 + g*8;
  for (int kk = 0; kk < 16; kk++){
    u16x8 pa = *(const u16x8*)((char*)pw + (l15 << 10) + ((((kk << 2) + g) ^ e7) << 4));
#pragma unroll
    for (int nf = 0; nf < 4; nf++){
      u16x8 vb = *(const u16x8*)(vp + (size_t)nf*16*512 + kk*32);
      oacc[nf] = MFMA16(pa, vb, oacc[nf]);
    }
  }

  u16* op = aout + ((size_t)b*512 + fw + g*4) * 1024 + n*64 + l15;
#pragma unroll
  for (int nf = 0; nf < 4; nf++)
#pragma unroll
    for (int j = 0; j < 4; j++)
      op[(size_t)j*1024 + nf*16] = f2bf(oacc[nf][j] * invj[j]);
}

// ---------------- host ----------------
extern "C" void kernel_launch(void* const* d_in, const int* in_sizes, int n_in,
                              void* d_out, int out_size, void* d_ws, size_t ws_size,
                              hipStream_t stream){
  const float* dec_in   = (const float*)d_in[0];
  const float* enc      = (const float*)d_in[1];
  const float* dist     = (const float*)d_in[3];
  const float* abias    = (const float*)d_in[5];
  const float* Wq  = (const float*)d_in[6];
  const float* Wk  = (const float*)d_in[7];
  const float* Wv  = (const float*)d_in[8];
  const float* Wo  = (const float*)d_in[9];
  const float* Wth = (const float*)d_in[10];
  const float* bth = (const float*)d_in[11];
  const float* Wto = (const float*)d_in[12];
  const float* bto = (const float*)d_in[13];
  const float* Wf1 = (const float*)d_in[14];
  const float* bf1 = (const float*)d_in[15];
  const float* Wf2 = (const float*)d_in[16];
  const float* bf2 = (const float*)d_in[17];
  float* dout = (float*)d_out;

  char* wp = (char*)d_ws;
  auto alloc = [&](size_t n) -> char* {
    char* p = wp; wp += (n + 255) & ~(size_t)255; return p;
  };
  float* x     = (float*)alloc((size_t)1048576 * 4);
  u16*  xn     = (u16*)alloc((size_t)1048576 * 2);
  u16*  encb   = (u16*)alloc((size_t)1048576 * 2);
  u16*  Wqt    = (u16*)alloc((size_t)4194304 * 2);    // 4 layers
  u16*  Wkt    = (u16*)alloc((size_t)4194304 * 2);
  u16*  Wvt    = (u16*)alloc((size_t)4194304 * 2);
  u16*  Wot    = (u16*)alloc((size_t)4194304 * 2);
  u16*  Wf1t   = (u16*)alloc((size_t)16777216 * 2);   // 4 layers
  u16*  Wf2t   = (u16*)alloc((size_t)16777216 * 2);
  u16*  Kb     = (u16*)alloc((size_t)4194304 * 2);    // 4 layers
  u16*  Vt     = (u16*)alloc((size_t)4194304 * 2);
  u16*  qs     = (u16*)alloc((size_t)2097152 * 2);    // 4 layers, bf16
  u16*  aout   = (u16*)alloc((size_t)1048576 * 2);
  u16*  ffh    = (u16*)alloc((size_t)4194304 * 2);
  float* part  = (float*)alloc((size_t)4194304 * 4);  // 4x 1024x1024 f32

  // ---- upfront (2 dispatches) ----
  // prep_A: only what gemmKV needs (Wk/Wv transposes, enc) + LN of dec_in
  prepA_k<<<2560, 256, 0, stream>>>(Wk, Wv, enc, dec_in, x, xn, Wkt, Wvt, encb);
  // prep_B (Wq/Wo/Wf1/Wf2 transposes + qs) interleaved with gemmKV blocks
  prepB_gemmKV_k<<<5632, 256, 0, stream>>>(Wq, Wo, Wf1, Wf2, dist,
                                           Wth, bth, Wto, bto,
                                           encb, Wkt, Wvt,
                                           Wqt, Wot, Wf1t, Wf2t, qs, Kb, Vt);

  // ---- per-layer serial chain: 6 dispatches ----
  for (int i = 0; i < 4; i++){
    const size_t wo = (size_t)i * 1048576;

    // fused attention (Q-proj + logits + biases + softmax + PV)
    attn_k<<<dim3(16, 8, 2), 256, 0, stream>>>(xn, Wqt + wo, Kb + wo, Vt + wo,
                                               qs + (size_t)i * 524288, abias, aout);

    // O projection (split-K=4) + fused residual+LN
    gemm_splitk_k<<<dim3(16, 8, 4), 256, 0, stream>>>(aout, 1024, Wot + wo, 1024, 256, part);
    reduce_ln_k<0, 0><<<1024, 256, 0, stream>>>(part, nullptr, x, xn, nullptr);

    // FFN
    gemm128_k<3><<<dim3(64, 8), 256, 0, stream>>>(xn, 1024, Wf1t + (size_t)i*4194304, 1024,
                                                  1024, 4096, ffh, bf1 + (size_t)i*4096);
    gemm_splitk_k<<<dim3(16, 8, 4), 256, 0, stream>>>(ffh, 4096, Wf2t + (size_t)i*4194304, 4096,
                                                      1024, part);
    if (i < 3)
      reduce_ln_k<1, 0><<<1024, 256, 0, stream>>>(part, bf2 + (size_t)i*1024, x, xn, nullptr);
    else
      reduce_ln_k<1, 1><<<1024, 256, 0, stream>>>(part, bf2 + (size_t)i*1024, x, nullptr, dout);
  }
}